// Round 10
// baseline (208.813 us; speedup 1.0000x reference)
//
#include <hip/hip_runtime.h>
#include <hip/hip_bf16.h>
#include <math.h>

// Problem constants (B=4, C=192, H=W=128, KS=3, dilations {1,2,3}, 6 heads)
#define Hdim 128
#define Wdim 128
#define HW   16384
#define Cdim 192
#define Bdim 4
#define QKVC 576            // 3*C
#define NTOT (Bdim * HW)    // 65536 total pixels

typedef __attribute__((ext_vector_type(8))) short short8;   // 8 bf16 (4 VGPRs)
typedef __attribute__((ext_vector_type(4))) short short4v;  // 4 bf16 (8 B)
typedef __attribute__((ext_vector_type(4))) float f32x4;

__device__ __forceinline__ void async_ld16(void* lds, const void* g) {
    __builtin_amdgcn_global_load_lds(
        (const __attribute__((address_space(1))) void*)g,
        (__attribute__((address_space(3))) void*)lds, 16, 0, 0);
}
__device__ __forceinline__ float lo16(unsigned u) { return __uint_as_float(u << 16); }
__device__ __forceinline__ float hi16(unsigned u) { return __uint_as_float(u & 0xffff0000u); }

// ---------------------------------------------------------------------------
// Convert both weight matrices to bf16 (147456 elements total).
// ---------------------------------------------------------------------------
__global__ void convert_w(const float* __restrict__ qkv_w,
                          const float* __restrict__ proj_w,
                          __hip_bfloat16* __restrict__ Wq,
                          __hip_bfloat16* __restrict__ Wp) {
    int i = blockIdx.x * 256 + threadIdx.x;
    if (i < QKVC * Cdim) {
        Wq[i] = __float2bfloat16(qkv_w[i]);
    } else {
        int j = i - QKVC * Cdim;
        Wp[j] = __float2bfloat16(proj_w[j]);
    }
}

// ---------------------------------------------------------------------------
// posconv v2: depthwise 3x3 (zero pad) + bias + residual, f32 NCHW in ->
// bf16 NHWC out [NTOT][192]. Block = (image, row, 16-ch group); grid 6144.
// Rows {h-1,h,h+1} staged to LDS via global_load_lds (linear dest +
// chunk-swizzled global source, XOR on read). XCD banding for L2 halo reuse.
// ---------------------------------------------------------------------------
__global__ __launch_bounds__(256, 5)
void posconv_nhwc(const float* __restrict__ x,
                  const float* __restrict__ pos_w,
                  const float* __restrict__ pos_b,
                  __hip_bfloat16* __restrict__ Xb) {
    __shared__ __align__(16) float xs[3 * 16 * 128];      // 24 KB staged rows
    __shared__ __hip_bfloat16 tile[16][132];              // transpose tile

    int t = threadIdx.x;
    int id = blockIdx.x;                 // 0..6143
    int xj = id & 7;                     // XCD (dispatch round-robin)
    int r_ = id >> 3;                    // 0..767
    int rb = r_ & 15;
    int cg = (r_ >> 4) % 12;             // channel group 0..11
    int b  = (r_ >> 4) / 12;             // image 0..3
    int h  = xj * 16 + rb;               // row 0..127 (16-row band per XCD)

    int hh0 = h > 0 ? h - 1 : 0;
    int hh1 = h;
    int hh2 = h < Hdim - 1 ? h + 1 : Hdim - 1;

    int ch = t >> 4;                     // 0..15 within group
    int qh = t & 15;                     // 8-px span index
    int cglob = cg * 16 + ch;

    const float* wp = pos_w + cglob * 9;
    float w0 = wp[0], w1 = wp[1], w2 = wp[2];
    float w3 = wp[3], w4 = wp[4], w5 = wp[5];
    float w6 = wp[6], w7 = wp[7], w8 = wp[8];
    float bias = pos_b[cglob];
    float m0 = (h > 0) ? 1.f : 0.f;
    float m2 = (h < Hdim - 1) ? 1.f : 0.f;
    w0 *= m0; w1 *= m0; w2 *= m0;
    w6 *= m2; w7 *= m2; w8 *= m2;

    {
        const float* xg = x + (size_t)(b * Cdim + cg * 16) * HW;
#pragma unroll
        for (int k = 0; k < 6; ++k) {
            int u = t + k * 256;
            int rowi = u >> 5;           // 0..47 = rr*16 + sch
            int ql = u & 31;
            int rr = rowi >> 4;
            int sch = rowi & 15;
            int hr = rr == 0 ? hh0 : (rr == 1 ? hh1 : hh2);
            int qs = ql ^ sch;           // swizzle involution
            async_ld16((char*)xs + (size_t)u * 16,
                       xg + (size_t)sch * HW + hr * Wdim + qs * 4);
        }
    }
    __syncthreads();

    float out[8];
    {
        const char* xsb = (const char*)xs;
        const char* r0b = xsb + (size_t)(0 * 16 + ch) * 512;
        const char* r1b = xsb + (size_t)(1 * 16 + ch) * 512;
        const char* r2b = xsb + (size_t)(2 * 16 + ch) * 512;
        float4 lo0 = *(const float4*)(r0b + (((2 * qh)     ^ ch) * 16));
        float4 hi0 = *(const float4*)(r0b + (((2 * qh + 1) ^ ch) * 16));
        float4 lo1 = *(const float4*)(r1b + (((2 * qh)     ^ ch) * 16));
        float4 hi1 = *(const float4*)(r1b + (((2 * qh + 1) ^ ch) * 16));
        float4 lo2 = *(const float4*)(r2b + (((2 * qh)     ^ ch) * 16));
        float4 hi2 = *(const float4*)(r2b + (((2 * qh + 1) ^ ch) * 16));
        float L0 = __shfl_up(hi0.w, 1, 64), R0 = __shfl_down(lo0.x, 1, 64);
        float L1 = __shfl_up(hi1.w, 1, 64), R1 = __shfl_down(lo1.x, 1, 64);
        float L2 = __shfl_up(hi2.w, 1, 64), R2 = __shfl_down(lo2.x, 1, 64);
        if (qh == 0)  { L0 = 0.f; L1 = 0.f; L2 = 0.f; }   // image left edge
        if (qh == 15) { R0 = 0.f; R1 = 0.f; R2 = 0.f; }   // image right edge
        float a0[10] = {L0, lo0.x, lo0.y, lo0.z, lo0.w, hi0.x, hi0.y, hi0.z, hi0.w, R0};
        float a1[10] = {L1, lo1.x, lo1.y, lo1.z, lo1.w, hi1.x, hi1.y, hi1.z, hi1.w, R1};
        float a2[10] = {L2, lo2.x, lo2.y, lo2.z, lo2.w, hi2.x, hi2.y, hi2.z, hi2.w, R2};
#pragma unroll
        for (int i = 0; i < 8; ++i) {
            out[i] = a1[i + 1] + bias
                   + w0 * a0[i] + w1 * a0[i + 1] + w2 * a0[i + 2]
                   + w3 * a1[i] + w4 * a1[i + 1] + w5 * a1[i + 2]
                   + w6 * a2[i] + w7 * a2[i + 1] + w8 * a2[i + 2];
        }
    }

    union { unsigned short u[8]; short8 v; } pk;
#pragma unroll
    for (int i = 0; i < 8; ++i) {
        __hip_bfloat16 bv = __float2bfloat16(out[i]);
        pk.u[i] = *(unsigned short*)&bv;
    }
    *(short8*)(void*)&tile[ch][qh * 8] = pk.v;
    __syncthreads();

    int px = t >> 1, s2 = t & 1;
    union { unsigned short u[8]; short8 v; } o;
#pragma unroll
    for (int j = 0; j < 8; ++j)
        o.u[j] = *(const unsigned short*)&tile[s2 * 8 + j][px];
    size_t p0img = (size_t)(b << 14) + (size_t)h * Wdim;
    *(short8*)(void*)(Xb + (p0img + px) * Cdim + cg * 16 + s2 * 8) = o.v;
}

// ---------------------------------------------------------------------------
// MFMA bf16 GEMM (QKV projection): D[m,n] = sum_k W[m,k] * Xt[n,k]  (K=192)
// Block 64x256 (4 waves of 64x64, 4x4 frags of 16x16x32). BK=32, dbuf LDS,
// stage(kt+1) issued before compute(kt), one barrier per K-step. 3 blocks/CU.
// XCD-aware decode. B = NHWC [NTOT][192]; stores bf16 planes
// [(three*3+pi)*2+pn][NTOT][32].
// ---------------------------------------------------------------------------
template <int MODE, int MT>
__global__ __launch_bounds__(256, 3)
void gemm_mfma(const __hip_bfloat16* __restrict__ Wb,
               const __hip_bfloat16* __restrict__ Xt,
               void* __restrict__ Cout) {
    __shared__ __hip_bfloat16 As[2][64 * 32];
    __shared__ __hip_bfloat16 Bs[2][256 * 32];
    const int t = threadIdx.x;
    const int w = t >> 6, l = t & 63;
    const int lq = l >> 4, lr = l & 15;
    const int id = blockIdx.x;
    const int xj = id & 7;                 // XCD (dispatch round-robin)
    const int rest = id >> 3;
    const int m0 = (rest % MT) * 64;
    const int n0 = ((rest / MT) * 8 + xj) * 256;

    const int ms = t >> 2, kcs = t & 3;    // A-staging coords (per thread)

    auto stage = [&](int buf, int kt_) {
        const int k0_ = kt_ * 32;
        async_ld16(As[buf] + t * 8,
                   Wb + (size_t)(m0 + ms) * Cdim + k0_ + kcs * 8);
#pragma unroll
        for (int it = 0; it < 4; ++it) {
            int idx = it * 256 + t;
            int n = idx >> 2, kc = idx & 3;
            const __hip_bfloat16* src;
            if (MODE == 0)
                src = Xt + (size_t)(n0 + n) * Cdim + k0_ + kc * 8;
            else
                src = Xt + (size_t)kt_ * ((size_t)NTOT * 32) +
                      (size_t)(n0 + n) * 32 + kc * 8;
            async_ld16(Bs[buf] + idx * 8, src);
        }
    };

    f32x4 acc[4][4] = {};

    stage(0, 0);
    __syncthreads();                       // drain prologue DMA

#pragma unroll
    for (int kt = 0; kt < 6; ++kt) {
        const int cur = kt & 1;
        if (kt < 5) stage(cur ^ 1, kt + 1);   // issue next tile FIRST

        short8 af[4], bf[4];
#pragma unroll
        for (int i = 0; i < 4; ++i)
            af[i] = *(const short8*)(void*)(As[cur] + (i * 16 + lr) * 32 + lq * 8);
#pragma unroll
        for (int j = 0; j < 4; ++j)
            bf[j] = *(const short8*)(void*)(Bs[cur] + (w * 64 + j * 16 + lr) * 32 + lq * 8);
#pragma unroll
        for (int i = 0; i < 4; ++i)
#pragma unroll
            for (int j = 0; j < 4; ++j)
                acc[i][j] = __builtin_amdgcn_mfma_f32_16x16x32_bf16(
                    af[i], bf[j], acc[i][j], 0, 0, 0);

        __syncthreads();                   // drains next-tile DMA + buf reuse
    }

    // epilogue: D col = lane&15, row = (lane>>4)*4 + r  (m89/m91-verified)
#pragma unroll
    for (int i = 0; i < 4; ++i) {
        int mb = m0 + i * 16 + lq * 4;            // 4 consecutive m (r=0..3)
#pragma unroll
        for (int j = 0; j < 4; ++j) {
            int n = n0 + w * 64 + j * 16 + lr;
            if (MODE == 0) {
                int three = mb / 192, rem = mb % 192;
                int pi = rem >> 6, pn = (rem >> 5) & 1, d4 = rem & 31;
                size_t plane = (size_t)((three * 3 + pi) * 2 + pn);
                __hip_bfloat16* dst = (__hip_bfloat16*)Cout +
                    plane * ((size_t)NTOT * 32) + (size_t)n * 32 + d4;
                short4v pk;
#pragma unroll
                for (int r = 0; r < 4; ++r) {
                    __hip_bfloat16 bv = __float2bfloat16(acc[i][j][r]);
                    pk[r] = *(short*)&bv;
                }
                *(short4v*)(void*)dst = pk;
            } else {
                int b = n >> 14, p = n & (HW - 1);
#pragma unroll
                for (int r = 0; r < 4; ++r)
                    ((float*)Cout)[((size_t)(b * Cdim + mb + r)) * HW + p] =
                        acc[i][j][r];
            }
        }
    }
}

// ---------------------------------------------------------------------------
// FUSED attention + proj, v2c. Block = (image b, row h), 512 threads, grid 512.
// Register-pressure-shaped so (512,2)'s 128-VGPR cap holds WITHOUT spills
// (r8: (512,4)=64 cap -> 212 MB spill; r9: qv[6]+pa+pacc[12] peak >128 ->
// 82 MB spill). Two structural cuts:
//  - Q DOUBLE-BUFFER (8 VGPRs) instead of qv[6] preload (24): load Q(c+1)
//    at the top of comb c's compute.
//  - proj in TWO HALVES of 6 output tiles: pacc[6] (24 VGPRs) per pass,
//    re-doing the 24 cheap pa shuffles; peak proj = pa24+pacc24 ~ 60.
// Structure otherwise = v2: kv single buffer [6][8192] (48 KiB), per comb
// compute -> bar -> stage(c+1) -> bar; attn out in registers pa[6][4];
// MFMA B-frag via in-wave shuffle transpose (src lane = (l&15)*4 + (l>>4));
// Wp staged rows of 25 chunks (odd stride); LDS 76800 -> 2 blocks/CU.
// XCD banding: adjacent rows per XCD -> K/V halo rows L2-hit.
// ---------------------------------------------------------------------------
__global__ __launch_bounds__(512, 2)
void attn_proj(const __hip_bfloat16* __restrict__ QKV,
               const __hip_bfloat16* __restrict__ Wpg,
               float* __restrict__ out) {
    __shared__ __align__(16) unsigned char smem[76800];
    unsigned char* kv  = smem;              // [6 rows][8192 B] during attn
    unsigned char* wpl = smem;              // [192 o][400 B] during proj

    const int t = threadIdx.x;
    const int px = t >> 2, s = t & 3;       // pixel, 8-dim slice
    const int id = blockIdx.x;              // 0..511
    const int xj = id & 7, rest = id >> 3;
    const int b = rest >> 4, rb = rest & 15;
    const int h = xj * 16 + rb;             // 16-row band per XCD
    const size_t PS = (size_t)NTOT * 32;
    const size_t colbase = (size_t)(b << 14) + (size_t)h * Wdim;

    const int g = t ^ ((t >> 3) & 7);       // stage chunk swizzle (involution)

    auto loadQ = [&](int c) -> uint4 {
        return *((const uint4*)(QKV + (size_t)c * PS + (colbase + px) * 32) + s);
    };
    auto stageKV = [&](int comb) {
        int dil = (comb >> 1) + 1;
#pragma unroll
        for (int kh = 0; kh < 3; ++kh) {
            int v = h + (kh - 1) * dil;     // reflect pad
            v = v < 0 ? -v : (v >= Hdim ? 2 * Hdim - 2 - v : v);
            size_t rowe = ((size_t)(b << 14) + (size_t)v * Wdim) * 32;
            async_ld16(kv + (kh * 512 + t) * 16,
                       QKV + (size_t)(6 + comb) * PS + rowe + g * 8);
            async_ld16(kv + ((kh + 3) * 512 + t) * 16,
                       QKV + (size_t)(12 + comb) * PS + rowe + g * 8);
        }
    };

    unsigned pa[6][4];                      // attn out: 8 bf16/comb, packed

    uint4 qcur = loadQ(0);
    stageKV(0);
    __syncthreads();                        // drain prologue

#pragma unroll
    for (int c = 0; c < 6; ++c) {
        uint4 qnext;
        if (c < 5) qnext = loadQ(c + 1);    // in flight under compute+barriers

        {   // ---- attention for comb c from kv ----
            const int dil = (c >> 1) + 1;
            float q[8];
            {
                uint4 x = qcur;
                q[0] = lo16(x.x); q[1] = hi16(x.x);
                q[2] = lo16(x.y); q[3] = hi16(x.y);
                q[4] = lo16(x.z); q[5] = hi16(x.z);
                q[6] = lo16(x.w); q[7] = hi16(x.w);
            }
            int coff[3];
#pragma unroll
            for (int kw = 0; kw < 3; ++kw) {
                int ww = px + (kw - 1) * dil;
                ww = ww < 0 ? -ww : (ww >= Wdim ? 2 * Wdim - 2 - ww : ww);
                int i0 = 4 * ww + s;
                coff[kw] = (i0 ^ ((i0 >> 3) & 7)) * 16;
            }
            float sc[9];
#pragma unroll
            for (int kh = 0; kh < 3; ++kh)
#pragma unroll
                for (int kw = 0; kw < 3; ++kw) {
                    uint4 xk = *(const uint4*)(void*)(kv + kh * 8192 + coff[kw]);
                    sc[kh * 3 + kw] =
                          q[0] * lo16(xk.x) + q[1] * hi16(xk.x)
                        + q[2] * lo16(xk.y) + q[3] * hi16(xk.y)
                        + q[4] * lo16(xk.z) + q[5] * hi16(xk.z)
                        + q[6] * lo16(xk.w) + q[7] * hi16(xk.w);
                }
            // 4-lane butterfly: full 32-d dot in every lane of the quad
#pragma unroll
            for (int j = 0; j < 9; ++j) {
                float v = sc[j];
                v += __shfl_xor(v, 1, 64);
                v += __shfl_xor(v, 2, 64);
                sc[j] = v * 0.17677669529663687f;   // 1/sqrt(32)
            }
            float mx = sc[0];
#pragma unroll
            for (int j = 1; j < 9; ++j) mx = fmaxf(mx, sc[j]);
            float sum = 0.f;
#pragma unroll
            for (int j = 0; j < 9; ++j) { sc[j] = __expf(sc[j] - mx); sum += sc[j]; }
            float inv = 1.f / sum;

            float a8[8] = {};
#pragma unroll
            for (int kh = 0; kh < 3; ++kh)
#pragma unroll
                for (int kw = 0; kw < 3; ++kw) {
                    float a = sc[kh * 3 + kw];
                    uint4 xv = *(const uint4*)(void*)(kv + (kh + 3) * 8192 + coff[kw]);
                    a8[0] += a * lo16(xv.x); a8[1] += a * hi16(xv.x);
                    a8[2] += a * lo16(xv.y); a8[3] += a * hi16(xv.y);
                    a8[4] += a * lo16(xv.z); a8[5] += a * hi16(xv.z);
                    a8[6] += a * lo16(xv.w); a8[7] += a * hi16(xv.w);
                }
            // pack 8 bf16 into 4 dwords (dims 2j low, 2j+1 high)
#pragma unroll
            for (int j = 0; j < 4; ++j) {
                __hip_bfloat16 blo = __float2bfloat16(a8[2 * j]     * inv);
                __hip_bfloat16 bhi = __float2bfloat16(a8[2 * j + 1] * inv);
                pa[c][j] = (unsigned)*(unsigned short*)&blo |
                           ((unsigned)*(unsigned short*)&bhi << 16);
            }
        }
        __syncthreads();                    // all waves done reading kv
        if (c < 5) {
            stageKV(c + 1);                 // overwrite kv (single buffer)
            __syncthreads();                // drain DMA before next compute
        }
        qcur = qnext;
    }

    // ---- stage Wp [192][192] -> LDS rows of 25 chunks (24 data + 1 pad) ----
    // 4800 chunks; guard at 192 threads = 3 whole waves (wave-uniform).
#pragma unroll
    for (int k = 0; k < 10; ++k) {
        if (k < 9 || t < 192) {
            int cidx = t + k * 512;
            int row = cidx / 25, cc = cidx - row * 25;  // cc==24 -> pad
            async_ld16(wpl + (size_t)cidx * 16, Wpg + row * 192 + cc * 8);
        }
    }
    __syncthreads();                        // drain Wp

    // ---- proj: out[o][px] = sum_c Wp[o][c] * ao[px][c], MFMA 16x16x32 ----
    // Two passes of 6 output tiles to halve accumulator pressure.
    const int wv = t >> 6, l = t & 63;
    const int lq = l >> 4, lr = l & 15;
    const int srcl = (l & 15) * 4 + (l >> 4);   // in-wave transpose source
    float* outp = out + (size_t)b * Cdim * HW + (size_t)h * Wdim;
    const int pxn = wv * 16 + lr;
#pragma unroll
    for (int half = 0; half < 2; ++half) {
        f32x4 pacc[6] = {};
#pragma unroll
        for (int kt = 0; kt < 6; ++kt) {
            union { unsigned d[4]; short8 v; } bu;
#pragma unroll
            for (int j = 0; j < 4; ++j)
                bu.d[j] = (unsigned)__shfl((int)pa[kt][j], srcl, 64);
            short8 bfrag = bu.v;
#pragma unroll
            for (int i2 = 0; i2 < 6; ++i2) {
                int i = half * 6 + i2;
                short8 afrag = *(const short8*)(void*)
                    (wpl + (size_t)((i * 16 + lr) * 25 + kt * 4 + lq) * 16);
                pacc[i2] = __builtin_amdgcn_mfma_f32_16x16x32_bf16(
                    afrag, bfrag, pacc[i2], 0, 0, 0);
            }
        }
        // D: col = lane&15 -> px, row = lq*4 + r -> o (m89/m91-verified)
#pragma unroll
        for (int i2 = 0; i2 < 6; ++i2) {
            int o = (half * 6 + i2) * 16 + lq * 4;
#pragma unroll
            for (int r = 0; r < 4; ++r)
                outp[(size_t)(o + r) * HW + pxn] = pacc[i2][r];
        }
    }
}

// ---------------------------------------------------------------------------
extern "C" void kernel_launch(void* const* d_in, const int* in_sizes, int n_in,
                              void* d_out, int out_size, void* d_ws, size_t ws_size,
                              hipStream_t stream) {
    const float* x      = (const float*)d_in[0];
    const float* pos_w  = (const float*)d_in[1];
    const float* pos_b  = (const float*)d_in[2];
    const float* qkv_w  = (const float*)d_in[3];
    const float* proj_w = (const float*)d_in[4];
    float* out = (float*)d_out;

    // ws layout (bytes): Xb 24 MiB | QKV planes 72 MiB | (unused) | Wq | Wp
    char* ws = (char*)d_ws;
    __hip_bfloat16* Xb  = (__hip_bfloat16*)ws;                            // [NTOT][192]
    __hip_bfloat16* QKV = (__hip_bfloat16*)(ws + (size_t)25165824);       // [18][NTOT][32]
    __hip_bfloat16* Wq  = (__hip_bfloat16*)(ws + (size_t)125829120);      // [576][192]
    __hip_bfloat16* Wp  = (__hip_bfloat16*)(ws + (size_t)126050304);      // [192][192]

    convert_w<<<(QKVC * Cdim + Cdim * Cdim) / 256, 256, 0, stream>>>(
        qkv_w, proj_w, Wq, Wp);

    posconv_nhwc<<<6144, 256, 0, stream>>>(x, pos_w, pos_b, Xb);

    gemm_mfma<0, 9><<<2304, 256, 0, stream>>>(Wq, Xb, QKV);

    attn_proj<<<512, 512, 0, stream>>>(QKV, Wp, out);
}

// Round 11
// 181.804 us; speedup vs baseline: 1.1486x; 1.1486x over previous
//
#include <hip/hip_runtime.h>
#include <hip/hip_bf16.h>
#include <math.h>

// Problem constants (B=4, C=192, H=W=128, KS=3, dilations {1,2,3}, 6 heads)
#define Hdim 128
#define Wdim 128
#define HW   16384
#define Cdim 192
#define Bdim 4
#define QKVC 576            // 3*C
#define NTOT (Bdim * HW)    // 65536 total pixels

typedef __attribute__((ext_vector_type(8))) short short8;   // 8 bf16 (4 VGPRs)
typedef __attribute__((ext_vector_type(4))) short short4v;  // 4 bf16 (8 B)
typedef __attribute__((ext_vector_type(4))) float f32x4;

__device__ __forceinline__ void async_ld16(void* lds, const void* g) {
    __builtin_amdgcn_global_load_lds(
        (const __attribute__((address_space(1))) void*)g,
        (__attribute__((address_space(3))) void*)lds, 16, 0, 0);
}
__device__ __forceinline__ float lo16(unsigned u) { return __uint_as_float(u << 16); }
__device__ __forceinline__ float hi16(unsigned u) { return __uint_as_float(u & 0xffff0000u); }

// ---------------------------------------------------------------------------
// Convert both weight matrices to bf16 (147456 elements total).
// ---------------------------------------------------------------------------
__global__ void convert_w(const float* __restrict__ qkv_w,
                          const float* __restrict__ proj_w,
                          __hip_bfloat16* __restrict__ Wq,
                          __hip_bfloat16* __restrict__ Wp) {
    int i = blockIdx.x * 256 + threadIdx.x;
    if (i < QKVC * Cdim) {
        Wq[i] = __float2bfloat16(qkv_w[i]);
    } else {
        int j = i - QKVC * Cdim;
        Wp[j] = __float2bfloat16(proj_w[j]);
    }
}

// ---------------------------------------------------------------------------
// posconv v2: depthwise 3x3 (zero pad) + bias + residual, f32 NCHW in ->
// bf16 NHWC out [NTOT][192]. Block = (image, row, 16-ch group); grid 6144.
// Rows {h-1,h,h+1} staged to LDS via global_load_lds (linear dest +
// chunk-swizzled global source, XOR on read). XCD banding for L2 halo reuse.
// ---------------------------------------------------------------------------
__global__ __launch_bounds__(256, 5)
void posconv_nhwc(const float* __restrict__ x,
                  const float* __restrict__ pos_w,
                  const float* __restrict__ pos_b,
                  __hip_bfloat16* __restrict__ Xb) {
    __shared__ __align__(16) float xs[3 * 16 * 128];      // 24 KB staged rows
    __shared__ __hip_bfloat16 tile[16][132];              // transpose tile

    int t = threadIdx.x;
    int id = blockIdx.x;                 // 0..6143
    int xj = id & 7;                     // XCD (dispatch round-robin)
    int r_ = id >> 3;                    // 0..767
    int rb = r_ & 15;
    int cg = (r_ >> 4) % 12;             // channel group 0..11
    int b  = (r_ >> 4) / 12;             // image 0..3
    int h  = xj * 16 + rb;               // row 0..127 (16-row band per XCD)

    int hh0 = h > 0 ? h - 1 : 0;
    int hh1 = h;
    int hh2 = h < Hdim - 1 ? h + 1 : Hdim - 1;

    int ch = t >> 4;                     // 0..15 within group
    int qh = t & 15;                     // 8-px span index
    int cglob = cg * 16 + ch;

    const float* wp = pos_w + cglob * 9;
    float w0 = wp[0], w1 = wp[1], w2 = wp[2];
    float w3 = wp[3], w4 = wp[4], w5 = wp[5];
    float w6 = wp[6], w7 = wp[7], w8 = wp[8];
    float bias = pos_b[cglob];
    float m0 = (h > 0) ? 1.f : 0.f;
    float m2 = (h < Hdim - 1) ? 1.f : 0.f;
    w0 *= m0; w1 *= m0; w2 *= m0;
    w6 *= m2; w7 *= m2; w8 *= m2;

    {
        const float* xg = x + (size_t)(b * Cdim + cg * 16) * HW;
#pragma unroll
        for (int k = 0; k < 6; ++k) {
            int u = t + k * 256;
            int rowi = u >> 5;           // 0..47 = rr*16 + sch
            int ql = u & 31;
            int rr = rowi >> 4;
            int sch = rowi & 15;
            int hr = rr == 0 ? hh0 : (rr == 1 ? hh1 : hh2);
            int qs = ql ^ sch;           // swizzle involution
            async_ld16((char*)xs + (size_t)u * 16,
                       xg + (size_t)sch * HW + hr * Wdim + qs * 4);
        }
    }
    __syncthreads();

    float out[8];
    {
        const char* xsb = (const char*)xs;
        const char* r0b = xsb + (size_t)(0 * 16 + ch) * 512;
        const char* r1b = xsb + (size_t)(1 * 16 + ch) * 512;
        const char* r2b = xsb + (size_t)(2 * 16 + ch) * 512;
        float4 lo0 = *(const float4*)(r0b + (((2 * qh)     ^ ch) * 16));
        float4 hi0 = *(const float4*)(r0b + (((2 * qh + 1) ^ ch) * 16));
        float4 lo1 = *(const float4*)(r1b + (((2 * qh)     ^ ch) * 16));
        float4 hi1 = *(const float4*)(r1b + (((2 * qh + 1) ^ ch) * 16));
        float4 lo2 = *(const float4*)(r2b + (((2 * qh)     ^ ch) * 16));
        float4 hi2 = *(const float4*)(r2b + (((2 * qh + 1) ^ ch) * 16));
        float L0 = __shfl_up(hi0.w, 1, 64), R0 = __shfl_down(lo0.x, 1, 64);
        float L1 = __shfl_up(hi1.w, 1, 64), R1 = __shfl_down(lo1.x, 1, 64);
        float L2 = __shfl_up(hi2.w, 1, 64), R2 = __shfl_down(lo2.x, 1, 64);
        if (qh == 0)  { L0 = 0.f; L1 = 0.f; L2 = 0.f; }   // image left edge
        if (qh == 15) { R0 = 0.f; R1 = 0.f; R2 = 0.f; }   // image right edge
        float a0[10] = {L0, lo0.x, lo0.y, lo0.z, lo0.w, hi0.x, hi0.y, hi0.z, hi0.w, R0};
        float a1[10] = {L1, lo1.x, lo1.y, lo1.z, lo1.w, hi1.x, hi1.y, hi1.z, hi1.w, R1};
        float a2[10] = {L2, lo2.x, lo2.y, lo2.z, lo2.w, hi2.x, hi2.y, hi2.z, hi2.w, R2};
#pragma unroll
        for (int i = 0; i < 8; ++i) {
            out[i] = a1[i + 1] + bias
                   + w0 * a0[i] + w1 * a0[i + 1] + w2 * a0[i + 2]
                   + w3 * a1[i] + w4 * a1[i + 1] + w5 * a1[i + 2]
                   + w6 * a2[i] + w7 * a2[i + 1] + w8 * a2[i + 2];
        }
    }

    union { unsigned short u[8]; short8 v; } pk;
#pragma unroll
    for (int i = 0; i < 8; ++i) {
        __hip_bfloat16 bv = __float2bfloat16(out[i]);
        pk.u[i] = *(unsigned short*)&bv;
    }
    *(short8*)(void*)&tile[ch][qh * 8] = pk.v;
    __syncthreads();

    int px = t >> 1, s2 = t & 1;
    union { unsigned short u[8]; short8 v; } o;
#pragma unroll
    for (int j = 0; j < 8; ++j)
        o.u[j] = *(const unsigned short*)&tile[s2 * 8 + j][px];
    size_t p0img = (size_t)(b << 14) + (size_t)h * Wdim;
    *(short8*)(void*)(Xb + (p0img + px) * Cdim + cg * 16 + s2 * 8) = o.v;
}

// ---------------------------------------------------------------------------
// MFMA bf16 GEMM (QKV projection): D[m,n] = sum_k W[m,k] * Xt[n,k]  (K=192)
// Block 64x256 (4 waves of 64x64, 4x4 frags of 16x16x32). BK=32, dbuf LDS,
// stage(kt+1) issued before compute(kt), one barrier per K-step. 3 blocks/CU.
// XCD-aware decode. B = NHWC [NTOT][192]; stores bf16 planes
// [(three*3+pi)*2+pn][NTOT][32].
// ---------------------------------------------------------------------------
template <int MODE, int MT>
__global__ __launch_bounds__(256, 3)
void gemm_mfma(const __hip_bfloat16* __restrict__ Wb,
               const __hip_bfloat16* __restrict__ Xt,
               void* __restrict__ Cout) {
    __shared__ __hip_bfloat16 As[2][64 * 32];
    __shared__ __hip_bfloat16 Bs[2][256 * 32];
    const int t = threadIdx.x;
    const int w = t >> 6, l = t & 63;
    const int lq = l >> 4, lr = l & 15;
    const int id = blockIdx.x;
    const int xj = id & 7;                 // XCD (dispatch round-robin)
    const int rest = id >> 3;
    const int m0 = (rest % MT) * 64;
    const int n0 = ((rest / MT) * 8 + xj) * 256;

    const int ms = t >> 2, kcs = t & 3;    // A-staging coords (per thread)

    auto stage = [&](int buf, int kt_) {
        const int k0_ = kt_ * 32;
        async_ld16(As[buf] + t * 8,
                   Wb + (size_t)(m0 + ms) * Cdim + k0_ + kcs * 8);
#pragma unroll
        for (int it = 0; it < 4; ++it) {
            int idx = it * 256 + t;
            int n = idx >> 2, kc = idx & 3;
            const __hip_bfloat16* src;
            if (MODE == 0)
                src = Xt + (size_t)(n0 + n) * Cdim + k0_ + kc * 8;
            else
                src = Xt + (size_t)kt_ * ((size_t)NTOT * 32) +
                      (size_t)(n0 + n) * 32 + kc * 8;
            async_ld16(Bs[buf] + idx * 8, src);
        }
    };

    f32x4 acc[4][4] = {};

    stage(0, 0);
    __syncthreads();                       // drain prologue DMA

#pragma unroll
    for (int kt = 0; kt < 6; ++kt) {
        const int cur = kt & 1;
        if (kt < 5) stage(cur ^ 1, kt + 1);   // issue next tile FIRST

        short8 af[4], bf[4];
#pragma unroll
        for (int i = 0; i < 4; ++i)
            af[i] = *(const short8*)(void*)(As[cur] + (i * 16 + lr) * 32 + lq * 8);
#pragma unroll
        for (int j = 0; j < 4; ++j)
            bf[j] = *(const short8*)(void*)(Bs[cur] + (w * 64 + j * 16 + lr) * 32 + lq * 8);
#pragma unroll
        for (int i = 0; i < 4; ++i)
#pragma unroll
            for (int j = 0; j < 4; ++j)
                acc[i][j] = __builtin_amdgcn_mfma_f32_16x16x32_bf16(
                    af[i], bf[j], acc[i][j], 0, 0, 0);

        __syncthreads();                   // drains next-tile DMA + buf reuse
    }

    // epilogue: D col = lane&15, row = (lane>>4)*4 + r  (m89/m91-verified)
#pragma unroll
    for (int i = 0; i < 4; ++i) {
        int mb = m0 + i * 16 + lq * 4;            // 4 consecutive m (r=0..3)
#pragma unroll
        for (int j = 0; j < 4; ++j) {
            int n = n0 + w * 64 + j * 16 + lr;
            if (MODE == 0) {
                int three = mb / 192, rem = mb % 192;
                int pi = rem >> 6, pn = (rem >> 5) & 1, d4 = rem & 31;
                size_t plane = (size_t)((three * 3 + pi) * 2 + pn);
                __hip_bfloat16* dst = (__hip_bfloat16*)Cout +
                    plane * ((size_t)NTOT * 32) + (size_t)n * 32 + d4;
                short4v pk;
#pragma unroll
                for (int r = 0; r < 4; ++r) {
                    __hip_bfloat16 bv = __float2bfloat16(acc[i][j][r]);
                    pk[r] = *(short*)&bv;
                }
                *(short4v*)(void*)dst = pk;
            } else {
                int b = n >> 14, p = n & (HW - 1);
#pragma unroll
                for (int r = 0; r < 4; ++r)
                    ((float*)Cout)[((size_t)(b * Cdim + mb + r)) * HW + p] =
                        acc[i][j][r];
            }
        }
    }
}

// ---------------------------------------------------------------------------
// FUSED attention + proj (round-7 structure, stride fix). Block = (b, h),
// 512 threads, grid 512. Proven-clean codegen (r7: VGPR 88, no spills);
// register-ao variants (r8-r10) all spilled and are abandoned.
// Per comb (6, sequential, double-buffered K/V LDS): stage K/V rows
// {h-d,h,h+d} via global_load_lds (chunk-swizzled SOURCE, XOR on reads);
// 9-tap attention per (pixel, 8-dim slice); deposit bf16 into ao tile.
// THIS ROUND's one change: ao/Wp row stride 416 B (104 dw = 8 mod 32,
// 4-way bank conflict on bfrag/afrag reads -> 958K SQ_LDS_BANK_CONFLICT)
// -> 432 B (108 dw = 12 mod 32: start bank 4*((3*lr+lq)%8), 3*lr%8 is a
// permutation -> uniform 8 lanes/bank-quad = b128 floor).
// LDS = 98304 (kv dbuf) + 55296 (ao, 128x432) = 153600 -> 1 block/CU.
// ---------------------------------------------------------------------------
__global__ __launch_bounds__(512, 2)
void attn_proj(const __hip_bfloat16* __restrict__ QKV,
               const __hip_bfloat16* __restrict__ Wpg,
               float* __restrict__ out) {
    __shared__ __align__(16) unsigned char smem[153600];
    unsigned char* kv  = smem;              // [2 buf][6 rows][8192 B]
    unsigned char* aob = smem + 98304;      // [128 px][432 B] (216 bf16, pad)
    unsigned char* wpl = smem;              // [192 o][432 B]  (reuses kv)

    const int t = threadIdx.x;
    const int px = t >> 2, s = t & 3;       // pixel, 8-dim slice
    const int id = blockIdx.x;              // 0..511
    const int xj = id & 7, rest = id >> 3;
    const int b = rest >> 4, rb = rest & 15;
    const int h = xj * 16 + rb;             // 16-row band per XCD
    const size_t PS = (size_t)NTOT * 32;
    const size_t colbase = (size_t)(b << 14) + (size_t)h * Wdim;

    // preload all 6 Q fragments (16 B each; coalesced 4 KB/wave)
    uint4 qv[6];
#pragma unroll
    for (int c = 0; c < 6; ++c)
        qv[c] = *((const uint4*)(QKV + (size_t)c * PS + (colbase + px) * 32) + s);

    const int g = t ^ ((t >> 3) & 7);       // stage chunk swizzle (involution)

    auto stageKV = [&](int buf, int comb) {
        int dil = (comb >> 1) + 1;
        unsigned char* base = kv + buf * 49152;
#pragma unroll
        for (int kh = 0; kh < 3; ++kh) {
            int v = h + (kh - 1) * dil;     // reflect pad
            v = v < 0 ? -v : (v >= Hdim ? 2 * Hdim - 2 - v : v);
            size_t rowe = ((size_t)(b << 14) + (size_t)v * Wdim) * 32;
            async_ld16(base + (kh * 512 + t) * 16,
                       QKV + (size_t)(6 + comb) * PS + rowe + g * 8);
            async_ld16(base + ((kh + 3) * 512 + t) * 16,
                       QKV + (size_t)(12 + comb) * PS + rowe + g * 8);
        }
    };

    stageKV(0, 0);
    __syncthreads();                        // drain prologue

#pragma unroll
    for (int c = 0; c < 6; ++c) {
        if (c < 5) stageKV((c + 1) & 1, c + 1);   // next comb DMA in flight

        {   // ---- attention for comb c from kv[c&1] ----
            const int dil = (c >> 1) + 1;
            const unsigned char* base = kv + (c & 1) * 49152;
            float q[8];
            {
                uint4 x = qv[c];
                q[0] = lo16(x.x); q[1] = hi16(x.x);
                q[2] = lo16(x.y); q[3] = hi16(x.y);
                q[4] = lo16(x.z); q[5] = hi16(x.z);
                q[6] = lo16(x.w); q[7] = hi16(x.w);
            }
            int coff[3];
#pragma unroll
            for (int kw = 0; kw < 3; ++kw) {
                int ww = px + (kw - 1) * dil;
                ww = ww < 0 ? -ww : (ww >= Wdim ? 2 * Wdim - 2 - ww : ww);
                int i0 = 4 * ww + s;
                coff[kw] = (i0 ^ ((i0 >> 3) & 7)) * 16;
            }
            float sc[9];
#pragma unroll
            for (int kh = 0; kh < 3; ++kh)
#pragma unroll
                for (int kw = 0; kw < 3; ++kw) {
                    uint4 xk = *(const uint4*)(void*)(base + kh * 8192 + coff[kw]);
                    sc[kh * 3 + kw] =
                          q[0] * lo16(xk.x) + q[1] * hi16(xk.x)
                        + q[2] * lo16(xk.y) + q[3] * hi16(xk.y)
                        + q[4] * lo16(xk.z) + q[5] * hi16(xk.z)
                        + q[6] * lo16(xk.w) + q[7] * hi16(xk.w);
                }
            // 4-lane butterfly: full 32-d dot in every lane of the quad
#pragma unroll
            for (int j = 0; j < 9; ++j) {
                float v = sc[j];
                v += __shfl_xor(v, 1, 64);
                v += __shfl_xor(v, 2, 64);
                sc[j] = v * 0.17677669529663687f;   // 1/sqrt(32)
            }
            float mx = sc[0];
#pragma unroll
            for (int j = 1; j < 9; ++j) mx = fmaxf(mx, sc[j]);
            float sum = 0.f;
#pragma unroll
            for (int j = 0; j < 9; ++j) { sc[j] = __expf(sc[j] - mx); sum += sc[j]; }
            float inv = 1.f / sum;

            float a8[8] = {};
#pragma unroll
            for (int kh = 0; kh < 3; ++kh)
#pragma unroll
                for (int kw = 0; kw < 3; ++kw) {
                    float a = sc[kh * 3 + kw];
                    uint4 xv = *(const uint4*)(void*)(base + (kh + 3) * 8192 + coff[kw]);
                    a8[0] += a * lo16(xv.x); a8[1] += a * hi16(xv.x);
                    a8[2] += a * lo16(xv.y); a8[3] += a * hi16(xv.y);
                    a8[4] += a * lo16(xv.z); a8[5] += a * hi16(xv.z);
                    a8[6] += a * lo16(xv.w); a8[7] += a * hi16(xv.w);
                }
            union { unsigned short u[8]; short8 v; } pk;
#pragma unroll
            for (int d2 = 0; d2 < 8; ++d2) {
                __hip_bfloat16 bv = __float2bfloat16(a8[d2] * inv);
                pk.u[d2] = *(unsigned short*)&bv;
            }
            // ao channel = comb*32 + s*8 + j  (matches Wp column order)
            *(short8*)(void*)(aob + px * 432 + c * 64 + s * 16) = pk.v;
        }
        __syncthreads();                    // drains next-comb DMA; ao visible
    }

    // ---- stage Wp [192][192] -> LDS rows of 27 chunks (24 data + 3 pad) ----
    // 5184 chunks; last iteration guard t<64 = first wave (wave-uniform).
#pragma unroll
    for (int k = 0; k < 11; ++k) {
        if (k < 10 || t < 64) {
            int cidx = t + k * 512;
            int row = cidx / 27, cc = cidx - row * 27;  // cc>=24 -> pad
            async_ld16(wpl + (size_t)cidx * 16, Wpg + row * 192 + cc * 8);
        }
    }
    __syncthreads();                        // drain Wp

    // ---- proj: out[o][px] = sum_c Wp[o][c] * ao[px][c], MFMA 16x16x32 ----
    const int wv = t >> 6, l = t & 63;
    const int lq = l >> 4, lr = l & 15;
    f32x4 pacc[12] = {};
#pragma unroll
    for (int kt = 0; kt < 6; ++kt) {
        short8 bfrag = *(const short8*)(void*)
            (aob + (wv * 16 + lr) * 432 + kt * 64 + lq * 16);
#pragma unroll
        for (int i = 0; i < 12; ++i) {
            short8 afrag = *(const short8*)(void*)
                (wpl + (size_t)((i * 16 + lr) * 27 + kt * 4 + lq) * 16);
            pacc[i] = __builtin_amdgcn_mfma_f32_16x16x32_bf16(
                afrag, bfrag, pacc[i], 0, 0, 0);
        }
    }
    // D: col = lane&15 -> px, row = lq*4 + r -> o  (same mapping as gemm)
    float* outp = out + (size_t)b * Cdim * HW + (size_t)h * Wdim;
#pragma unroll
    for (int i = 0; i < 12; ++i) {
        int o = i * 16 + lq * 4;
        int pxn = wv * 16 + lr;
#pragma unroll
        for (int r = 0; r < 4; ++r)
            outp[(size_t)(o + r) * HW + pxn] = pacc[i][r];
    }
}

// ---------------------------------------------------------------------------
extern "C" void kernel_launch(void* const* d_in, const int* in_sizes, int n_in,
                              void* d_out, int out_size, void* d_ws, size_t ws_size,
                              hipStream_t stream) {
    const float* x      = (const float*)d_in[0];
    const float* pos_w  = (const float*)d_in[1];
    const float* pos_b  = (const float*)d_in[2];
    const float* qkv_w  = (const float*)d_in[3];
    const float* proj_w = (const float*)d_in[4];
    float* out = (float*)d_out;

    // ws layout (bytes): Xb 24 MiB | QKV planes 72 MiB | (unused) | Wq | Wp
    char* ws = (char*)d_ws;
    __hip_bfloat16* Xb  = (__hip_bfloat16*)ws;                            // [NTOT][192]
    __hip_bfloat16* QKV = (__hip_bfloat16*)(ws + (size_t)25165824);       // [18][NTOT][32]
    __hip_bfloat16* Wq  = (__hip_bfloat16*)(ws + (size_t)125829120);      // [576][192]
    __hip_bfloat16* Wp  = (__hip_bfloat16*)(ws + (size_t)126050304);      // [192][192]

    convert_w<<<(QKVC * Cdim + Cdim * Cdim) / 256, 256, 0, stream>>>(
        qkv_w, proj_w, Wq, Wp);

    posconv_nhwc<<<6144, 256, 0, stream>>>(x, pos_w, pos_b, Xb);

    gemm_mfma<0, 9><<<2304, 256, 0, stream>>>(Wq, Xb, QKV);

    attn_proj<<<512, 512, 0, stream>>>(QKV, Wp, out);
}

// Round 12
// 172.799 us; speedup vs baseline: 1.2084x; 1.0521x over previous
//
#include <hip/hip_runtime.h>
#include <hip/hip_bf16.h>
#include <math.h>

// Problem constants (B=4, C=192, H=W=128, KS=3, dilations {1,2,3}, 6 heads)
#define Hdim 128
#define Wdim 128
#define HW   16384
#define Cdim 192
#define Bdim 4
#define QKVC 576            // 3*C
#define NTOT (Bdim * HW)    // 65536 total pixels

typedef __attribute__((ext_vector_type(8))) short short8;   // 8 bf16 (4 VGPRs)
typedef __attribute__((ext_vector_type(4))) short short4v;  // 4 bf16 (8 B)
typedef __attribute__((ext_vector_type(4))) float f32x4;

__device__ __forceinline__ void async_ld16(void* lds, const void* g) {
    __builtin_amdgcn_global_load_lds(
        (const __attribute__((address_space(1))) void*)g,
        (__attribute__((address_space(3))) void*)lds, 16, 0, 0);
}
__device__ __forceinline__ float lo16(unsigned u) { return __uint_as_float(u << 16); }
__device__ __forceinline__ float hi16(unsigned u) { return __uint_as_float(u & 0xffff0000u); }

// ---------------------------------------------------------------------------
// Convert both weight matrices to bf16 (147456 elements total).
// ---------------------------------------------------------------------------
__global__ void convert_w(const float* __restrict__ qkv_w,
                          const float* __restrict__ proj_w,
                          __hip_bfloat16* __restrict__ Wq,
                          __hip_bfloat16* __restrict__ Wp) {
    int i = blockIdx.x * 256 + threadIdx.x;
    if (i < QKVC * Cdim) {
        Wq[i] = __float2bfloat16(qkv_w[i]);
    } else {
        int j = i - QKVC * Cdim;
        Wp[j] = __float2bfloat16(proj_w[j]);
    }
}

// ---------------------------------------------------------------------------
// posconv v2: depthwise 3x3 (zero pad) + bias + residual, f32 NCHW in ->
// bf16 NHWC out [NTOT][192]. Block = (image, row, 16-ch group); grid 6144.
// Rows {h-1,h,h+1} staged to LDS via global_load_lds (linear dest +
// chunk-swizzled global source, XOR on read). XCD banding for L2 halo reuse.
// ---------------------------------------------------------------------------
__global__ __launch_bounds__(256, 5)
void posconv_nhwc(const float* __restrict__ x,
                  const float* __restrict__ pos_w,
                  const float* __restrict__ pos_b,
                  __hip_bfloat16* __restrict__ Xb) {
    __shared__ __align__(16) float xs[3 * 16 * 128];      // 24 KB staged rows
    __shared__ __hip_bfloat16 tile[16][132];              // transpose tile

    int t = threadIdx.x;
    int id = blockIdx.x;                 // 0..6143
    int xj = id & 7;                     // XCD (dispatch round-robin)
    int r_ = id >> 3;                    // 0..767
    int rb = r_ & 15;
    int cg = (r_ >> 4) % 12;             // channel group 0..11
    int b  = (r_ >> 4) / 12;             // image 0..3
    int h  = xj * 16 + rb;               // row 0..127 (16-row band per XCD)

    int hh0 = h > 0 ? h - 1 : 0;
    int hh1 = h;
    int hh2 = h < Hdim - 1 ? h + 1 : Hdim - 1;

    int ch = t >> 4;                     // 0..15 within group
    int qh = t & 15;                     // 8-px span index
    int cglob = cg * 16 + ch;

    const float* wp = pos_w + cglob * 9;
    float w0 = wp[0], w1 = wp[1], w2 = wp[2];
    float w3 = wp[3], w4 = wp[4], w5 = wp[5];
    float w6 = wp[6], w7 = wp[7], w8 = wp[8];
    float bias = pos_b[cglob];
    float m0 = (h > 0) ? 1.f : 0.f;
    float m2 = (h < Hdim - 1) ? 1.f : 0.f;
    w0 *= m0; w1 *= m0; w2 *= m0;
    w6 *= m2; w7 *= m2; w8 *= m2;

    {
        const float* xg = x + (size_t)(b * Cdim + cg * 16) * HW;
#pragma unroll
        for (int k = 0; k < 6; ++k) {
            int u = t + k * 256;
            int rowi = u >> 5;           // 0..47 = rr*16 + sch
            int ql = u & 31;
            int rr = rowi >> 4;
            int sch = rowi & 15;
            int hr = rr == 0 ? hh0 : (rr == 1 ? hh1 : hh2);
            int qs = ql ^ sch;           // swizzle involution
            async_ld16((char*)xs + (size_t)u * 16,
                       xg + (size_t)sch * HW + hr * Wdim + qs * 4);
        }
    }
    __syncthreads();

    float out[8];
    {
        const char* xsb = (const char*)xs;
        const char* r0b = xsb + (size_t)(0 * 16 + ch) * 512;
        const char* r1b = xsb + (size_t)(1 * 16 + ch) * 512;
        const char* r2b = xsb + (size_t)(2 * 16 + ch) * 512;
        float4 lo0 = *(const float4*)(r0b + (((2 * qh)     ^ ch) * 16));
        float4 hi0 = *(const float4*)(r0b + (((2 * qh + 1) ^ ch) * 16));
        float4 lo1 = *(const float4*)(r1b + (((2 * qh)     ^ ch) * 16));
        float4 hi1 = *(const float4*)(r1b + (((2 * qh + 1) ^ ch) * 16));
        float4 lo2 = *(const float4*)(r2b + (((2 * qh)     ^ ch) * 16));
        float4 hi2 = *(const float4*)(r2b + (((2 * qh + 1) ^ ch) * 16));
        float L0 = __shfl_up(hi0.w, 1, 64), R0 = __shfl_down(lo0.x, 1, 64);
        float L1 = __shfl_up(hi1.w, 1, 64), R1 = __shfl_down(lo1.x, 1, 64);
        float L2 = __shfl_up(hi2.w, 1, 64), R2 = __shfl_down(lo2.x, 1, 64);
        if (qh == 0)  { L0 = 0.f; L1 = 0.f; L2 = 0.f; }   // image left edge
        if (qh == 15) { R0 = 0.f; R1 = 0.f; R2 = 0.f; }   // image right edge
        float a0[10] = {L0, lo0.x, lo0.y, lo0.z, lo0.w, hi0.x, hi0.y, hi0.z, hi0.w, R0};
        float a1[10] = {L1, lo1.x, lo1.y, lo1.z, lo1.w, hi1.x, hi1.y, hi1.z, hi1.w, R1};
        float a2[10] = {L2, lo2.x, lo2.y, lo2.z, lo2.w, hi2.x, hi2.y, hi2.z, hi2.w, R2};
#pragma unroll
        for (int i = 0; i < 8; ++i) {
            out[i] = a1[i + 1] + bias
                   + w0 * a0[i] + w1 * a0[i + 1] + w2 * a0[i + 2]
                   + w3 * a1[i] + w4 * a1[i + 1] + w5 * a1[i + 2]
                   + w6 * a2[i] + w7 * a2[i + 1] + w8 * a2[i + 2];
        }
    }

    union { unsigned short u[8]; short8 v; } pk;
#pragma unroll
    for (int i = 0; i < 8; ++i) {
        __hip_bfloat16 bv = __float2bfloat16(out[i]);
        pk.u[i] = *(unsigned short*)&bv;
    }
    *(short8*)(void*)&tile[ch][qh * 8] = pk.v;
    __syncthreads();

    int px = t >> 1, s2 = t & 1;
    union { unsigned short u[8]; short8 v; } o;
#pragma unroll
    for (int j = 0; j < 8; ++j)
        o.u[j] = *(const unsigned short*)&tile[s2 * 8 + j][px];
    size_t p0img = (size_t)(b << 14) + (size_t)h * Wdim;
    *(short8*)(void*)(Xb + (p0img + px) * Cdim + cg * 16 + s2 * 8) = o.v;
}

// ---------------------------------------------------------------------------
// MFMA bf16 GEMM (QKV projection): D[m,n] = sum_k W[m,k] * Xt[n,k]  (K=192)
// Block 64x256 (4 waves of 64x64, 4x4 frags of 16x16x32). BK=32, dbuf LDS,
// stage(kt+1) issued before compute(kt), one barrier per K-step. 3 blocks/CU.
// XCD-aware decode. B = NHWC [NTOT][192]; stores bf16 planes
// [(three*3+pi)*2+pn][NTOT][32].
// ---------------------------------------------------------------------------
template <int MODE, int MT>
__global__ __launch_bounds__(256, 3)
void gemm_mfma(const __hip_bfloat16* __restrict__ Wb,
               const __hip_bfloat16* __restrict__ Xt,
               void* __restrict__ Cout) {
    __shared__ __hip_bfloat16 As[2][64 * 32];
    __shared__ __hip_bfloat16 Bs[2][256 * 32];
    const int t = threadIdx.x;
    const int w = t >> 6, l = t & 63;
    const int lq = l >> 4, lr = l & 15;
    const int id = blockIdx.x;
    const int xj = id & 7;                 // XCD (dispatch round-robin)
    const int rest = id >> 3;
    const int m0 = (rest % MT) * 64;
    const int n0 = ((rest / MT) * 8 + xj) * 256;

    const int ms = t >> 2, kcs = t & 3;    // A-staging coords (per thread)

    auto stage = [&](int buf, int kt_) {
        const int k0_ = kt_ * 32;
        async_ld16(As[buf] + t * 8,
                   Wb + (size_t)(m0 + ms) * Cdim + k0_ + kcs * 8);
#pragma unroll
        for (int it = 0; it < 4; ++it) {
            int idx = it * 256 + t;
            int n = idx >> 2, kc = idx & 3;
            const __hip_bfloat16* src;
            if (MODE == 0)
                src = Xt + (size_t)(n0 + n) * Cdim + k0_ + kc * 8;
            else
                src = Xt + (size_t)kt_ * ((size_t)NTOT * 32) +
                      (size_t)(n0 + n) * 32 + kc * 8;
            async_ld16(Bs[buf] + idx * 8, src);
        }
    };

    f32x4 acc[4][4] = {};

    stage(0, 0);
    __syncthreads();                       // drain prologue DMA

#pragma unroll
    for (int kt = 0; kt < 6; ++kt) {
        const int cur = kt & 1;
        if (kt < 5) stage(cur ^ 1, kt + 1);   // issue next tile FIRST

        short8 af[4], bf[4];
#pragma unroll
        for (int i = 0; i < 4; ++i)
            af[i] = *(const short8*)(void*)(As[cur] + (i * 16 + lr) * 32 + lq * 8);
#pragma unroll
        for (int j = 0; j < 4; ++j)
            bf[j] = *(const short8*)(void*)(Bs[cur] + (w * 64 + j * 16 + lr) * 32 + lq * 8);
#pragma unroll
        for (int i = 0; i < 4; ++i)
#pragma unroll
            for (int j = 0; j < 4; ++j)
                acc[i][j] = __builtin_amdgcn_mfma_f32_16x16x32_bf16(
                    af[i], bf[j], acc[i][j], 0, 0, 0);

        __syncthreads();                   // drains next-tile DMA + buf reuse
    }

    // epilogue: D col = lane&15, row = (lane>>4)*4 + r  (m89/m91-verified)
#pragma unroll
    for (int i = 0; i < 4; ++i) {
        int mb = m0 + i * 16 + lq * 4;            // 4 consecutive m (r=0..3)
#pragma unroll
        for (int j = 0; j < 4; ++j) {
            int n = n0 + w * 64 + j * 16 + lr;
            if (MODE == 0) {
                int three = mb / 192, rem = mb % 192;
                int pi = rem >> 6, pn = (rem >> 5) & 1, d4 = rem & 31;
                size_t plane = (size_t)((three * 3 + pi) * 2 + pn);
                __hip_bfloat16* dst = (__hip_bfloat16*)Cout +
                    plane * ((size_t)NTOT * 32) + (size_t)n * 32 + d4;
                short4v pk;
#pragma unroll
                for (int r = 0; r < 4; ++r) {
                    __hip_bfloat16 bv = __float2bfloat16(acc[i][j][r]);
                    pk[r] = *(short*)&bv;
                }
                *(short4v*)(void*)dst = pk;
            } else {
                int b = n >> 14, p = n & (HW - 1);
#pragma unroll
                for (int r = 0; r < 4; ++r)
                    ((float*)Cout)[((size_t)(b * Cdim + mb + r)) * HW + p] =
                        acc[i][j][r];
            }
        }
    }
}

// ---------------------------------------------------------------------------
// FUSED attention + proj, v3: half-row blocks for occupancy.
// Block = (image b, row h, half w0), 256 threads (4 waves), grid 1024.
// LDS 53248 -> 3 blocks/CU = 12 waves/CU, independently progressing (r7/r11
// measured 1 block/CU x 8 lockstep waves = 17.7% occupancy = the limiter;
// bank conflicts measured at only ~4.5% overhead, not the lever).
//  - per comb: stage K/V rows {h-d,h,h+d} restricted to a 72-px window
//    [ws, ws+72), ws = w0==0 ? 0 : 56. Reflection maps all halo pixels back
//    into this window (dil<=3, verified both halves). Single kv buffer;
//    restage latency covered by the 2 other resident blocks.
//  - ao tile 64 px x 400 B; proj: Wp staged in THIRDS (64 rows x 25 chunks
//    = 25600 B <= kv region), pacc[4] per pass, bfrags precomputed.
// XCD banding: adjacent same-XCD blocks share K/V rows -> L2 hits.
// ---------------------------------------------------------------------------
__global__ __launch_bounds__(256, 3)
void attn_proj(const __hip_bfloat16* __restrict__ QKV,
               const __hip_bfloat16* __restrict__ Wpg,
               float* __restrict__ out) {
    __shared__ __align__(16) unsigned char smem[53248];
    unsigned char* kv  = smem;              // [6 rows][288 chunks][16] = 27648
    unsigned char* aob = smem + 27648;      // [64 px][400 B] = 25600
    unsigned char* wpl = smem;              // [64 o][400 B] per third (reuses kv)

    const int t = threadIdx.x;
    const int pxl = t >> 2, s = t & 3;      // local pixel 0..63, 8-dim slice
    const int id = blockIdx.x;              // 0..1023
    const int xj = id & 7, rest = id >> 3;  // XCD banding
    const int b = rest >> 5;                // image
    const int k5 = rest & 31;
    const int h = xj * 16 + (k5 >> 1);      // row (16-row band per XCD)
    const int w0 = (k5 & 1) * 64;           // half-row base
    const int ws = (w0 == 0) ? 0 : 56;      // 72-px staging window start
    const size_t PS = (size_t)NTOT * 32;
    const size_t colbase = (size_t)(b << 14) + (size_t)h * Wdim;

    // preload all 6 Q fragments (16 B each)
    uint4 qv[6];
#pragma unroll
    for (int c = 0; c < 6; ++c)
        qv[c] = *((const uint4*)(QKV + (size_t)c * PS +
                                 (colbase + w0 + pxl) * 32) + s);

    auto stageKV = [&](int comb) {
        int dil = (comb >> 1) + 1;
        int hh[3];
#pragma unroll
        for (int kh = 0; kh < 3; ++kh) {
            int v = h + (kh - 1) * dil;     // reflect pad
            hh[kh] = v < 0 ? -v : (v >= Hdim ? 2 * Hdim - 2 - v : v);
        }
        // 6 rows x 288 chunks = 1728; k=6 guard t<192 is wave-uniform (4 waves)
#pragma unroll
        for (int k = 0; k < 7; ++k) {
            if (k < 6 || t < 192) {
                int c = t + k * 256;
                int r = c / 288;
                int cc = c - r * 288;
                int kh = (r >= 3) ? r - 3 : r;
                int plane = (r >= 3) ? 12 + comb : 6 + comb;
                int gc = cc ^ ((cc >> 3) & 7);   // swizzle involution
                size_t rowe = ((size_t)(b << 14) +
                               (size_t)hh[kh] * Wdim + ws) * 32;
                async_ld16(kv + (size_t)c * 16,
                           QKV + (size_t)plane * PS + rowe + gc * 8);
            }
        }
    };

    stageKV(0);
    __syncthreads();                        // drain prologue

#pragma unroll
    for (int c = 0; c < 6; ++c) {
        {   // ---- attention for comb c from kv ----
            const int dil = (c >> 1) + 1;
            float q[8];
            {
                uint4 x = qv[c];
                q[0] = lo16(x.x); q[1] = hi16(x.x);
                q[2] = lo16(x.y); q[3] = hi16(x.y);
                q[4] = lo16(x.z); q[5] = hi16(x.z);
                q[6] = lo16(x.w); q[7] = hi16(x.w);
            }
            int coff[3];
#pragma unroll
            for (int kw = 0; kw < 3; ++kw) {
                int ww = w0 + pxl + (kw - 1) * dil;
                ww = ww < 0 ? -ww : (ww >= Wdim ? 2 * Wdim - 2 - ww : ww);
                int i0 = 4 * (ww - ws) + s;      // chunk in [0,288)
                coff[kw] = (i0 ^ ((i0 >> 3) & 7)) * 16;
            }
            float sc[9];
#pragma unroll
            for (int kh = 0; kh < 3; ++kh)
#pragma unroll
                for (int kw = 0; kw < 3; ++kw) {
                    uint4 xk = *(const uint4*)(void*)(kv + kh * 4608 + coff[kw]);
                    sc[kh * 3 + kw] =
                          q[0] * lo16(xk.x) + q[1] * hi16(xk.x)
                        + q[2] * lo16(xk.y) + q[3] * hi16(xk.y)
                        + q[4] * lo16(xk.z) + q[5] * hi16(xk.z)
                        + q[6] * lo16(xk.w) + q[7] * hi16(xk.w);
                }
            // 4-lane butterfly: full 32-d dot in every lane of the quad
#pragma unroll
            for (int j = 0; j < 9; ++j) {
                float v = sc[j];
                v += __shfl_xor(v, 1, 64);
                v += __shfl_xor(v, 2, 64);
                sc[j] = v * 0.17677669529663687f;   // 1/sqrt(32)
            }
            float mx = sc[0];
#pragma unroll
            for (int j = 1; j < 9; ++j) mx = fmaxf(mx, sc[j]);
            float sum = 0.f;
#pragma unroll
            for (int j = 0; j < 9; ++j) { sc[j] = __expf(sc[j] - mx); sum += sc[j]; }
            float inv = 1.f / sum;

            float a8[8] = {};
#pragma unroll
            for (int kh = 0; kh < 3; ++kh)
#pragma unroll
                for (int kw = 0; kw < 3; ++kw) {
                    float a = sc[kh * 3 + kw];
                    uint4 xv = *(const uint4*)(void*)
                        (kv + (kh + 3) * 4608 + coff[kw]);
                    a8[0] += a * lo16(xv.x); a8[1] += a * hi16(xv.x);
                    a8[2] += a * lo16(xv.y); a8[3] += a * hi16(xv.y);
                    a8[4] += a * lo16(xv.z); a8[5] += a * hi16(xv.z);
                    a8[6] += a * lo16(xv.w); a8[7] += a * hi16(xv.w);
                }
            union { unsigned short u[8]; short8 v; } pk;
#pragma unroll
            for (int d2 = 0; d2 < 8; ++d2) {
                __hip_bfloat16 bv = __float2bfloat16(a8[d2] * inv);
                pk.u[d2] = *(unsigned short*)&bv;
            }
            // ao channel = comb*32 + s*8 + j  (matches Wp column order)
            *(short8*)(void*)(aob + pxl * 400 + c * 64 + s * 16) = pk.v;
        }
        __syncthreads();                    // all waves done reading kv
        if (c < 5) {
            stageKV(c + 1);                 // overwrite kv (single buffer)
            __syncthreads();                // drain DMA before next compute
        }
    }

    // ---- proj: out[o][px] = sum_c Wp[o][c] * ao[px][c], MFMA 16x16x32 ----
    const int wv = t >> 6, l = t & 63;
    const int lq = l >> 4, lr = l & 15;
    const int pxn = wv * 16 + lr;           // local px of this lane's D col
    float* outp = out + (size_t)b * Cdim * HW + (size_t)h * Wdim + w0;

    short8 bfr[6];                          // B-fragments (ao), reused 3x
#pragma unroll
    for (int kt = 0; kt < 6; ++kt)
        bfr[kt] = *(const short8*)(void*)(aob + pxn * 400 + kt * 64 + lq * 16);

#pragma unroll
    for (int third = 0; third < 3; ++third) {
        // stage Wp rows [third*64, third*64+64) -> wpl rows of 25 chunks
        // 1600 chunks; k=6 guard t<64 = wave 0 (wave-uniform)
#pragma unroll
        for (int k = 0; k < 7; ++k) {
            if (k < 6 || t < 64) {
                int c = t + k * 256;
                int row = c / 25, cc = c - row * 25;   // cc==24 -> pad
                async_ld16(wpl + (size_t)c * 16,
                           Wpg + (third * 64 + row) * 192 + cc * 8);
            }
        }
        __syncthreads();                    // drain Wp third

        f32x4 pacc[4] = {};
#pragma unroll
        for (int kt = 0; kt < 6; ++kt) {
#pragma unroll
            for (int i2 = 0; i2 < 4; ++i2) {
                short8 afrag = *(const short8*)(void*)
                    (wpl + (size_t)((i2 * 16 + lr) * 25 + kt * 4 + lq) * 16);
                pacc[i2] = __builtin_amdgcn_mfma_f32_16x16x32_bf16(
                    afrag, bfr[kt], pacc[i2], 0, 0, 0);
            }
        }
        // D: col = lane&15 -> px, row = lq*4 + r -> o (m89/m91-verified)
#pragma unroll
        for (int i2 = 0; i2 < 4; ++i2) {
            int o = third * 64 + i2 * 16 + lq * 4;
#pragma unroll
            for (int r = 0; r < 4; ++r)
                outp[(size_t)(o + r) * HW + pxn] = pacc[i2][r];
        }
        if (third < 2) __syncthreads();     // reads done before next stage
    }
}

// ---------------------------------------------------------------------------
extern "C" void kernel_launch(void* const* d_in, const int* in_sizes, int n_in,
                              void* d_out, int out_size, void* d_ws, size_t ws_size,
                              hipStream_t stream) {
    const float* x      = (const float*)d_in[0];
    const float* pos_w  = (const float*)d_in[1];
    const float* pos_b  = (const float*)d_in[2];
    const float* qkv_w  = (const float*)d_in[3];
    const float* proj_w = (const float*)d_in[4];
    float* out = (float*)d_out;

    // ws layout (bytes): Xb 24 MiB | QKV planes 72 MiB | (unused) | Wq | Wp
    char* ws = (char*)d_ws;
    __hip_bfloat16* Xb  = (__hip_bfloat16*)ws;                            // [NTOT][192]
    __hip_bfloat16* QKV = (__hip_bfloat16*)(ws + (size_t)25165824);       // [18][NTOT][32]
    __hip_bfloat16* Wq  = (__hip_bfloat16*)(ws + (size_t)125829120);      // [576][192]
    __hip_bfloat16* Wp  = (__hip_bfloat16*)(ws + (size_t)126050304);      // [192][192]

    convert_w<<<(QKVC * Cdim + Cdim * Cdim) / 256, 256, 0, stream>>>(
        qkv_w, proj_w, Wq, Wp);

    posconv_nhwc<<<6144, 256, 0, stream>>>(x, pos_w, pos_b, Xb);

    gemm_mfma<0, 9><<<2304, 256, 0, stream>>>(Wq, Xb, QKV);

    attn_proj<<<1024, 256, 0, stream>>>(QKV, Wp, out);
}